// Round 6
// baseline (332.936 us; speedup 1.0000x reference)
//
#include <hip/hip_runtime.h>
#include <math.h>

// Problem constants
#define B_ROWS 65536
#define D_DIM  768
#define S_DIM  64
#define T_PTS  17

// Workspace layout. Accumulators (zeroed by norm_kernel) in first 3840 floats.
#define WS_COLSUM 0       // 768  : per-dim sum of z
#define WS_COLSQ  768     // 768  : per-dim sumsq of z
#define WS_PSUM   1536    // 64   : per-col sum of proj
#define WS_PSQ    1600    // 64   : per-col sumsq of proj
#define WS_ECFR   1664    // 17*64: sum cos
#define WS_ECFI   2752    // 17*64: sum sin (ends 3840)
#define WS_BT_HI_S 7680   // SHORT offset (== float offset 3840): bT[64][768] bf16
#define WS_PROJ   53248   // float offset: proj [65536 x 64]

typedef __attribute__((ext_vector_type(8))) short short8;   // 8 bf16 = 4 VGPR
typedef __attribute__((ext_vector_type(4))) short short4v;  // 4 bf16 = 2 VGPR
typedef __attribute__((ext_vector_type(4))) float float4v;

#define MFMA_BF16 __builtin_amdgcn_mfma_f32_16x16x32_bf16

static __device__ inline unsigned short f2bf(float x) {   // RNE fp32->bf16
    unsigned u = __float_as_uint(x);
    u += 0x7FFFu + ((u >> 16) & 1u);
    return (unsigned short)(u >> 16);
}

// ---------------- dirs: normalize, bf16, TRANSPOSE to [s][k]; zero accums.
__global__ void norm_kernel(const float* __restrict__ dirs, float* __restrict__ ws) {
    int s = blockIdx.x;
    int t = threadIdx.x;
    if (s < 60) ws[s * 64 + t] = 0.f;   // zero accums 0..3839 every call

    float sum = 0.f;
    #pragma unroll
    for (int j = 0; j < 12; ++j) {
        float v = dirs[(size_t)(t + j * 64) * S_DIM + s];
        sum += v * v;
    }
    #pragma unroll
    for (int m = 32; m; m >>= 1) sum += __shfl_xor(sum, m, 64);
    float invn = 1.0f / sqrtf(sum);

    unsigned short* bt = (unsigned short*)ws + WS_BT_HI_S;
    #pragma unroll
    for (int j = 0; j < 12; ++j) {
        int k = t + j * 64;
        bt[s * D_DIM + k] = f2bf(dirs[(size_t)k * S_DIM + s] * invn);
    }
}

// ---------------- main: pure-bf16 MFMA GEMM (proj = z @ dn) + fused colstats
// 512 blocks x 256 threads (4 waves). Block tile: 128 rows x 64 s, BK=64.
// LDS ~34 KB -> 3 blocks/CU: inter-block phase sliding hides HBM + barriers.
__global__ __launch_bounds__(256, 3) void main_kernel(const float* __restrict__ z,
                                                      float* __restrict__ ws) {
    __shared__ __align__(16) short zs[128 * 72];   // A tile bf16, stride 72
    __shared__ __align__(16) short bs[64 * 72];    // B tile bf16 [s][k]
    __shared__ float colacc[1536];                 // per-block colstat accumulator

    const unsigned short* bt = (const unsigned short*)ws + WS_BT_HI_S;
    float* proj = ws + WS_PROJ;

    int tid = threadIdx.x;
    int tx = tid & 15, ty = tid >> 4;        // staging: tx -> 4 k, ty + 16j -> rows
    int l = tid & 63, l15 = l & 15, q = l >> 4;
    int waveId = tid >> 6;
    int waveRow = waveId * 32;               // each wave: 32 rows x 64 s
    size_t rowbase = (size_t)blockIdx.x * 128;

    #pragma unroll
    for (int j = 0; j < 6; ++j) colacc[tid + j * 256] = 0.f;
    __syncthreads();                         // colacc zero before first ds_add

    float4v acc[2][4] = {};                  // [rowtile][stile]

    for (int c = 0; c < D_DIM / 64; ++c) {
        int kc = c * 64;

        // ---- stage A: global fp32 -> bf16, + colstat register partials
        float ps0 = 0, ps1 = 0, ps2 = 0, ps3 = 0;
        float pq0 = 0, pq1 = 0, pq2 = 0, pq3 = 0;
        #pragma unroll
        for (int j = 0; j < 8; ++j) {
            int rr = ty + 16 * j;
            float4 v = *reinterpret_cast<const float4*>(
                z + (rowbase + rr) * D_DIM + kc + tx * 4);
            ps0 += v.x; pq0 = fmaf(v.x, v.x, pq0);
            ps1 += v.y; pq1 = fmaf(v.y, v.y, pq1);
            ps2 += v.z; pq2 = fmaf(v.z, v.z, pq2);
            ps3 += v.w; pq3 = fmaf(v.w, v.w, pq3);
            short4v h4;
            h4.x = (short)f2bf(v.x); h4.y = (short)f2bf(v.y);
            h4.z = (short)f2bf(v.z); h4.w = (short)f2bf(v.w);
            *reinterpret_cast<short4v*>(&zs[rr * 72 + tx * 4]) = h4;
        }

        // ---- stage B tile (bf16 [s][k], L2-hot 96 KB table)
        {
            int srow = tid >> 2;
            int kpart = (tid & 3) * 16;
            short8 b0 = *(const short8*)(bt + (size_t)srow * D_DIM + kc + kpart);
            short8 b1 = *(const short8*)(bt + (size_t)srow * D_DIM + kc + kpart + 8);
            *(short8*)&bs[srow * 72 + kpart]     = b0;
            *(short8*)&bs[srow * 72 + kpart + 8] = b1;
        }

        // ---- colstat wave-reduce (over ty-in-wave via q lanes) + LDS atomics
        ps0 += __shfl_xor(ps0, 16, 64); ps0 += __shfl_xor(ps0, 32, 64);
        ps1 += __shfl_xor(ps1, 16, 64); ps1 += __shfl_xor(ps1, 32, 64);
        ps2 += __shfl_xor(ps2, 16, 64); ps2 += __shfl_xor(ps2, 32, 64);
        ps3 += __shfl_xor(ps3, 16, 64); ps3 += __shfl_xor(ps3, 32, 64);
        pq0 += __shfl_xor(pq0, 16, 64); pq0 += __shfl_xor(pq0, 32, 64);
        pq1 += __shfl_xor(pq1, 16, 64); pq1 += __shfl_xor(pq1, 32, 64);
        pq2 += __shfl_xor(pq2, 16, 64); pq2 += __shfl_xor(pq2, 32, 64);
        pq3 += __shfl_xor(pq3, 16, 64); pq3 += __shfl_xor(pq3, 32, 64);
        if (l < 16) {   // q==0 lanes hold wave-sums for cols tx*4..+3
            atomicAdd(&colacc[kc + tx * 4 + 0], ps0);
            atomicAdd(&colacc[kc + tx * 4 + 1], ps1);
            atomicAdd(&colacc[kc + tx * 4 + 2], ps2);
            atomicAdd(&colacc[kc + tx * 4 + 3], ps3);
            atomicAdd(&colacc[768 + kc + tx * 4 + 0], pq0);
            atomicAdd(&colacc[768 + kc + tx * 4 + 1], pq1);
            atomicAdd(&colacc[768 + kc + tx * 4 + 2], pq2);
            atomicAdd(&colacc[768 + kc + tx * 4 + 3], pq3);
        }
        __syncthreads();

        // ---- MFMA phase
        short8 ah[2][2];
        #pragma unroll
        for (int rt = 0; rt < 2; ++rt) {
            int aoff = (waveRow + rt * 16 + l15) * 72 + q * 8;
            ah[rt][0] = *(const short8*)&zs[aoff];
            ah[rt][1] = *(const short8*)&zs[aoff + 32];
        }
        #pragma unroll
        for (int st = 0; st < 4; ++st) {
            int boff = (st * 16 + l15) * 72 + q * 8;
            short8 bh0 = *(const short8*)&bs[boff];
            short8 bh1 = *(const short8*)&bs[boff + 32];
            #pragma unroll
            for (int rt = 0; rt < 2; ++rt) {
                acc[rt][st] = MFMA_BF16(ah[rt][0], bh0, acc[rt][st], 0, 0, 0);
                acc[rt][st] = MFMA_BF16(ah[rt][1], bh1, acc[rt][st], 0, 0, 0);
            }
        }
        __syncthreads();
    }

    // ---- flush colstats to global: one atomic sweep per block
    #pragma unroll
    for (int j = 0; j < 6; ++j) {
        int idx = tid + j * 256;             // maps 1:1 onto ws[0..1535]
        atomicAdd(&ws[idx], colacc[idx]);
    }

    // ---- epilogue: proj write (D layout: row=q*4+reg, col=l&15)
    #pragma unroll
    for (int rt = 0; rt < 2; ++rt)
        #pragma unroll
        for (int st = 0; st < 4; ++st) {
            int col = st * 16 + l15;
            size_t rbase = rowbase + waveRow + rt * 16 + q * 4;
            float4v v = acc[rt][st];
            proj[(rbase + 0) * S_DIM + col] = v[0];
            proj[(rbase + 1) * S_DIM + col] = v[1];
            proj[(rbase + 2) * S_DIM + col] = v[2];
            proj[(rbase + 3) * S_DIM + col] = v[3];
        }

    // ---- proj column stats: shfl over q, cross-wave via LDS scratch (reuse zs)
    float* scratch = reinterpret_cast<float*>(zs);   // [4 waves][64 cols][2]
    float cs[4], cq[4];
    #pragma unroll
    for (int st = 0; st < 4; ++st) {
        float s_ = 0.f, q_ = 0.f;
        #pragma unroll
        for (int rt = 0; rt < 2; ++rt) {
            float4v v = acc[rt][st];
            s_ += v[0] + v[1] + v[2] + v[3];
            q_ += v[0]*v[0] + v[1]*v[1] + v[2]*v[2] + v[3]*v[3];
        }
        s_ += __shfl_xor(s_, 16, 64); s_ += __shfl_xor(s_, 32, 64);
        q_ += __shfl_xor(q_, 16, 64); q_ += __shfl_xor(q_, 32, 64);
        cs[st] = s_; cq[st] = q_;
    }
    if (l < 16) {
        #pragma unroll
        for (int st = 0; st < 4; ++st) {
            int col = st * 16 + l15;
            scratch[(waveId * 64 + col) * 2 + 0] = cs[st];
            scratch[(waveId * 64 + col) * 2 + 1] = cq[st];
        }
    }
    __syncthreads();
    if (tid < 128) {
        int which = tid >> 6, col = tid & 63;
        float v = 0.f;
        #pragma unroll
        for (int w = 0; w < 4; ++w) v += scratch[(w * 64 + col) * 2 + which];
        atomicAdd(&ws[(which ? WS_PSQ : WS_PSUM) + col], v);
    }
}

// ------------------------------------------------------------------ ECF sums
__global__ __launch_bounds__(256) void ecf_kernel(float* __restrict__ ws) {
    const float* proj = ws + WS_PROJ;
    int tid = threadIdx.x;
    int s = tid & 63, r = tid >> 6;

    __shared__ float s_mean[64], s_scale[64];
    if (tid < 64) {
        float sum = ws[WS_PSUM + tid], sq = ws[WS_PSQ + tid];
        float mean = sum / (float)B_ROWS;
        float var = (sq - (float)B_ROWS * mean * mean) / (float)(B_ROWS - 1);
        var = fmaxf(var, 0.f);
        s_mean[tid]  = mean;
        s_scale[tid] = 1.0f / (sqrtf(var) + 1e-8f);
    }
    __syncthreads();
    float mean  = s_mean[s];
    float scale = s_scale[s];
    const float dt = 2.0f / 17.0f;

    float ar[T_PTS] = {}, ai[T_PTS] = {};
    size_t base = (size_t)blockIdx.x * 64;
    for (int i = 0; i < 16; ++i) {
        size_t row = base + i * 4 + r;
        float p  = proj[row * S_DIM + s];
        float ph = (p - mean) * scale;
        float a  = dt * ph;
        float s1, c1;
        __sincosf(a, &s1, &c1);
        float cc = c1, sn = s1;
        ar[0] += cc; ai[0] += sn;
        #pragma unroll
        for (int k = 1; k < T_PTS; ++k) {
            float cn = cc * c1 - sn * s1;
            sn = fmaf(sn, c1, cc * s1);
            cc = cn;
            ar[k] += cc; ai[k] += sn;
        }
    }

    __shared__ float red[3 * 2 * T_PTS * 64];
    if (r > 0) {
        float* dst = red + (r - 1) * (2 * T_PTS * 64);
        #pragma unroll
        for (int k = 0; k < T_PTS; ++k) {
            dst[k * 64 + s]               = ar[k];
            dst[T_PTS * 64 + k * 64 + s]  = ai[k];
        }
    }
    __syncthreads();
    if (r == 0) {
        const int STRIDE = 2 * T_PTS * 64;
        #pragma unroll
        for (int k = 0; k < T_PTS; ++k) {
            float vr = ar[k] + red[k * 64 + s] + red[STRIDE + k * 64 + s]
                             + red[2 * STRIDE + k * 64 + s];
            float vi = ai[k] + red[T_PTS * 64 + k * 64 + s]
                             + red[STRIDE + T_PTS * 64 + k * 64 + s]
                             + red[2 * STRIDE + T_PTS * 64 + k * 64 + s];
            atomicAdd(&ws[WS_ECFR + k * 64 + s], vr);
            atomicAdd(&ws[WS_ECFI + k * 64 + s], vi);
        }
    }
}

// ------------------------------------------------------------------ final loss
__global__ __launch_bounds__(256) void loss_kernel(const float* __restrict__ ws,
                                                   float* __restrict__ out) {
    int tid = threadIdx.x;
    double local = 0.0;
    for (int d = tid; d < D_DIM; d += 256) {
        double sum = (double)ws[WS_COLSUM + d];
        double sq  = (double)ws[WS_COLSQ + d];
        double mean = sum / 65536.0;
        double var  = (sq - 65536.0 * mean * mean) / 65535.0;
        if (var < 0) var = 0;
        double rl = 1.0 - sqrt(var);
        if (rl < 0) rl = 0;
        local += rl / 768.0;
    }
    const double dt = 2.0 / 17.0;
    for (int idx = tid; idx < T_PTS * 64; idx += 256) {
        int i = idx >> 6;
        double t   = dt * (i + 1);
        double tcf = exp(-0.5 * t * t);
        double w   = (i == 0 || i == T_PTS - 1) ? dt * 0.5 : dt;
        double er = (double)ws[WS_ECFR + idx] / 65536.0;
        double ei = (double)ws[WS_ECFI + idx] / 65536.0;
        double term = er * er + ei * ei - 2.0 * er * tcf + tcf * tcf;
        local += w * term / 64.0;
    }
    __shared__ double red[256];
    red[tid] = local;
    __syncthreads();
    for (int off = 128; off > 0; off >>= 1) {
        if (tid < off) red[tid] += red[tid + off];
        __syncthreads();
    }
    if (tid == 0) out[0] = (float)red[0];
}

extern "C" void kernel_launch(void* const* d_in, const int* in_sizes, int n_in,
                              void* d_out, int out_size, void* d_ws, size_t ws_size,
                              hipStream_t stream) {
    const float* z    = (const float*)d_in[0];  // [65536, 768]
    const float* dirs = (const float*)d_in[1];  // [768, 64]
    float* out = (float*)d_out;                 // scalar fp32
    float* ws  = (float*)d_ws;

    norm_kernel<<<S_DIM, 64, 0, stream>>>(dirs, ws);   // zero accums + bf16/transpose B
    main_kernel<<<B_ROWS / 128, 256, 0, stream>>>(z, ws);
    ecf_kernel<<<B_ROWS / 64, 256, 0, stream>>>(ws);
    loss_kernel<<<1, 256, 0, stream>>>(ws, out);
}